// Round 10
// baseline (634.832 us; speedup 1.0000x reference)
//
#include <hip/hip_runtime.h>
#include <hip/hip_bf16.h>

typedef __attribute__((ext_vector_type(8))) short short8;
typedef __attribute__((ext_vector_type(4))) float f32x4;

static __device__ __forceinline__ f32x4 MFMA16(short8 a, short8 b, f32x4 c) {
    return __builtin_amdgcn_mfma_f32_16x16x32_bf16(a, b, c, 0, 0, 0);
}
static __device__ __forceinline__ unsigned short f2bf(float f) {
    union { __hip_bfloat16 h; unsigned short u; } c;
    c.h = __float2bfloat16(f);
    return c.u;
}
static __device__ __forceinline__ void gload16(const void* g, void* l) {
    __builtin_amdgcn_global_load_lds(
        (const __attribute__((address_space(1))) unsigned int*)g,
        (__attribute__((address_space(3))) unsigned int*)l, 16, 0, 0);
}

// ---------------- ws layout ----------------
// wst  : bf16, LDS-order pre-swizzled w_in  [6 hp][6 s][1536 granules x16B] @ 0        (884736)
// wos  : bf16, LDS-order pre-swizzled w_out [3 nb][6 s][1024 granules x16B] @ 884736   (294912)
// brr  : f32  [12][96] head-major bias                                      @ 1179648  (4608)
// attst: bf16, LDS-order pre-swizzled att   [1024 mb][6 s][16384 B]         @ 1184256  (100663296)
constexpr size_t kWstOff = 0;
constexpr size_t kWosOff = 884736;
constexpr size_t kBrrOff = 1179648;
constexpr size_t kAttOff = 1184256;

// ================= kernel 0: prep (convert + reorder + pre-swizzle weights) =====
__global__ void prep(const float* __restrict__ w_in, const float* __restrict__ b_in,
                     const float* __restrict__ w_out,
                     char* __restrict__ wst, char* __restrict__ wos,
                     float* __restrict__ brr)
{
    const int i = blockIdx.x * 256 + threadIdx.x;   // grid covers 73728 exactly
    if (i < 55296) {
        int hp = i / 9216, rem = i % 9216;
        int s = rem / 1536, slot16 = rem % 1536;
        int row = slot16 >> 3, sl = slot16 & 7;
        int c8 = sl ^ (row & 7);
        int hh = row / 96, rr = row % 96;
        int sec = rr >> 5, d = rr & 31;
        int srow = sec * 384 + (hp * 2 + hh) * 32 + d;
        int k0 = s * 64 + c8 * 8;
        const float4* src = (const float4*)(w_in + (size_t)srow * 384 + k0);
        float4 a = src[0], b = src[1];
        uint4 w;
        w.x = f2bf(a.x) | ((unsigned)f2bf(a.y) << 16);
        w.y = f2bf(a.z) | ((unsigned)f2bf(a.w) << 16);
        w.z = f2bf(b.x) | ((unsigned)f2bf(b.y) << 16);
        w.w = f2bf(b.z) | ((unsigned)f2bf(b.w) << 16);
        *(uint4*)(wst + (size_t)i * 16) = w;
    } else {
        int j = i - 55296;                           // [0, 18432)
        int nb = j / 6144, rem = j % 6144;
        int s = rem / 1024, slot16 = rem % 1024;
        int row = slot16 >> 3, sl = slot16 & 7;
        int c8 = sl ^ (row & 7);
        int srow = nb * 128 + row;
        int k0 = s * 64 + c8 * 8;
        const float4* src = (const float4*)(w_out + (size_t)srow * 384 + k0);
        float4 a = src[0], b = src[1];
        uint4 w;
        w.x = f2bf(a.x) | ((unsigned)f2bf(a.y) << 16);
        w.y = f2bf(a.z) | ((unsigned)f2bf(a.w) << 16);
        w.z = f2bf(b.x) | ((unsigned)f2bf(b.y) << 16);
        w.w = f2bf(b.z) | ((unsigned)f2bf(b.w) << 16);
        *(uint4*)(wos + (size_t)j * 16) = w;
    }
    if (i < 1152) {
        int h = i / 96, jj = i % 96;
        int sec = jj >> 5, d = jj & 31;
        brr[i] = b_in[sec * 384 + h * 32 + d];
    }
}

// ================= kernel A: QKV projection + window attention =================
// grid: 2048 m-blocks x 6 head-pairs = 12288. block = 512 thr (8 waves).
// BM=64 (4 windows), BN=192 (2 heads x q32|k32|v32), BK=64.
// A DIRECT from global x (f32 -> bf16 in-reg; L1-served); B in LDS, double-buffered.
// LDS 48KB: B 2x[192][128B] -> 3 blocks/CU; ONE barrier per K-step.
// attn alias: QKV^T tiles [4 win][2 head][3 sec][32 d][16 t] @0 (24KB, in B-buf0)
__global__ __launch_bounds__(512, 6)
void qkv_attn(const float* __restrict__ x, const char* __restrict__ wst,
              const float* __restrict__ brr, char* __restrict__ attst)
{
    __shared__ __align__(16) char smem[49152];

    const int tid  = threadIdx.x;
    const int lane = tid & 63, wid = tid >> 6;         // 8 waves
    const int g = lane >> 4, r16 = lane & 15;
    const int wm = wid >> 2, wn = wid & 3;             // wm 0..1 (M32), wn 0..3 (N48)

    int b = blockIdx.x;
    int L = (b & 7) * 1536 + (b >> 3);         // XCD-chunked swizzle (12288 % 8 == 0)
    const int mblk = L / 6, hp = L - mblk * 6;

    // ---- A row pointers: this lane's 2 token rows (window-remapped) ----
    const float* arow[2];
    #pragma unroll
    for (int mi = 0; mi < 2; ++mi) {
        int T = mblk * 64 + wm * 32 + mi * 16 + r16;
        int win0 = T >> 4, t4 = T & 15;
        int bb0 = win0 >> 8, wh = (win0 >> 4) & 15, ww = win0 & 15;
        arow[mi] = x + ((size_t)bb0 * 4096 +
                        (size_t)((wh * 4 + (t4 >> 2)) * 64 + ww * 4 + (t4 & 3))) * 384
                     + g * 8;
    }

    const char* wst_blk = wst + (size_t)hp * 147456;
    auto stage_B = [&](int s, int buf) {
        char* dst = smem + buf * 24576 + tid * 16;
        const char* src = wst_blk + s * 24576 + tid * 16;
        #pragma unroll
        for (int j = 0; j < 3; ++j) gload16(src + j * 8192, dst + j * 8192);
    };

    f32x4 acc[2][3] = {};
    auto compute = [&](int s, int buf) {
        const char* bbp = smem + buf * 24576;
        #pragma unroll
        for (int c = 0; c < 2; ++c) {
            const int sw = ((c * 4 + g) ^ (r16 & 7)) << 4;
            union UA { unsigned u[4]; short8 v; } a[2];
            #pragma unroll
            for (int mi = 0; mi < 2; ++mi) {
                const float4* ap = (const float4*)(arow[mi] + s * 64 + c * 32);
                float4 lo = ap[0], hi = ap[1];
                a[mi].u[0] = f2bf(lo.x) | ((unsigned)f2bf(lo.y) << 16);
                a[mi].u[1] = f2bf(lo.z) | ((unsigned)f2bf(lo.w) << 16);
                a[mi].u[2] = f2bf(hi.x) | ((unsigned)f2bf(hi.y) << 16);
                a[mi].u[3] = f2bf(hi.z) | ((unsigned)f2bf(hi.w) << 16);
            }
            short8 bf[3];
            #pragma unroll
            for (int ni = 0; ni < 3; ++ni)
                bf[ni] = *(const short8*)(bbp + (wn * 48 + ni * 16 + r16) * 128 + sw);
            #pragma unroll
            for (int mi = 0; mi < 2; ++mi)
                #pragma unroll
                for (int ni = 0; ni < 3; ++ni)
                    acc[mi][ni] = MFMA16(a[mi].v, bf[ni], acc[mi][ni]);
        }
    };

    // main loop: B double-buffered, ONE barrier per step; A streams from global
    stage_B(0, 0);
    for (int s = 0; s < 6; ++s) {
        __syncthreads();                       // B(s) DMA drained; prev buf free
        if (s < 5) stage_B(s + 1, (s + 1) & 1);
        compute(s, s & 1);
    }
    // Epilogue writes go to B-buf0 (24KB @0). At s=5 all waves read buf1 only,
    // and every wave passed bar(s=5) after finishing its buf0 reads -> safe, no
    // extra barrier needed here.

    // ---- epilogue: acc (+bias) -> Q^T/K^T/V^T tiles [win][head][sec][d][t] ----
    #pragma unroll
    for (int mi = 0; mi < 2; ++mi) {
        const int win = wm * 2 + mi;
        #pragma unroll
        for (int ni = 0; ni < 3; ++ni) {
            const int cb = wn * 48 + ni * 16;   // col base in [0,192), 16-aligned
            const int hl = cb / 96;             // head-local 0/1
            const int w96 = cb - hl * 96;
            const int sec = w96 >> 5;           // 0=Q 1=K 2=V
            const int d = (w96 & 31) + r16;
            const float bias = brr[(hp * 2 + hl) * 96 + w96 + r16];
            float v0 = acc[mi][ni][0] + bias;
            float v1 = acc[mi][ni][1] + bias;
            float v2 = acc[mi][ni][2] + bias;
            float v3 = acc[mi][ni][3] + bias;
            uint2 w;
            w.x = f2bf(v0) | ((unsigned)f2bf(v1) << 16);
            w.y = f2bf(v2) | ((unsigned)f2bf(v3) << 16);
            *(uint2*)(smem + win * 6144 + hl * 3072 + sec * 1024 + d * 32 + g * 8) = w;
        }
    }
    __syncthreads();  // tiles written cross-wave: rendezvous before attn

    // ---- attention: 1 (window, head) per wave, P stays in registers ----
    const float kC = 0.17677669529663687f * 1.4426950408889634f;  // (1/sqrt32)*log2e
    const f32x4 zero = {0.f, 0.f, 0.f, 0.f};
    {
        const int win = wid >> 1;
        const int hl  = wid & 1;
        char* base = smem + win * 6144 + hl * 3072;

        union U8 { unsigned short e[8]; short8 v; };
        U8 ku, qu;
        #pragma unroll
        for (int j = 0; j < 8; ++j) {
            const int off = (g * 8 + j) * 32 + r16 * 2;   // elem (d, t=r16)
            qu.e[j] = *(const unsigned short*)(base + off);
            ku.e[j] = *(const unsigned short*)(base + 1024 + off);
        }
        f32x4 s = MFMA16(ku.v, qu.v, zero);     // D[key=4g+r][q=r16]

        float m = fmaxf(fmaxf(s[0], s[1]), fmaxf(s[2], s[3]));
        m = fmaxf(m, __shfl_xor(m, 16, 64));
        m = fmaxf(m, __shfl_xor(m, 32, 64));
        float p[4], sum = 0.f;
        #pragma unroll
        for (int r = 0; r < 4; ++r) { p[r] = exp2f((s[r] - m) * kC); sum += p[r]; }
        sum += __shfl_xor(sum, 16, 64);
        sum += __shfl_xor(sum, 32, 64);
        const float inv = 1.f / sum;

        // P as in-register A-fragment under k-perm k=4g+j (upper 4 elems zero);
        // V's B-fragment uses the SAME key permutation.
        U8 pu;
        pu.e[0] = f2bf(p[0] * inv); pu.e[1] = f2bf(p[1] * inv);
        pu.e[2] = f2bf(p[2] * inv); pu.e[3] = f2bf(p[3] * inv);
        pu.e[4] = 0; pu.e[5] = 0; pu.e[6] = 0; pu.e[7] = 0;

        f32x4 o[2];
        #pragma unroll
        for (int ti = 0; ti < 2; ++ti) {
            U8 vu;                               // V[key=4g+j][d=ti*16+r16]
            *(uint2*)&vu.e[0] = *(const uint2*)(base + 2048 + (ti * 16 + r16) * 32 + g * 8);
            vu.e[4] = 0; vu.e[5] = 0; vu.e[6] = 0; vu.e[7] = 0;
            o[ti] = MFMA16(pu.v, vu.v, zero);    // D[q=4g+r][d-col=r16]
        }

        // transpose o via own tile's (dead) Q area -> [t][d] rows of 64B,
        // then ONE uint4 global store per lane in attst's swizzled-granule layout.
        #pragma unroll
        for (int ti = 0; ti < 2; ++ti)
            #pragma unroll
            for (int r = 0; r < 4; ++r)
                *(unsigned short*)(base + (g * 4 + r) * 64 + (ti * 16 + r16) * 2)
                    = f2bf(o[ti][r]);
        // same-wave LDS RAW: compiler inserts lgkmcnt wait
        uint4 ov = *(const uint4*)(base + r16 * 64 + g * 16);

        const int ghead = hp * 2 + hl;
        int gr = mblk * 64 + win * 16 + r16;     // global token row
        int mb = gr >> 7, row7 = gr & 127;
        int col8 = ghead * 4 + g;                // 16B-granule column index
        int sst = col8 >> 3;
        int sl = (col8 & 7) ^ (row7 & 7);
        *(uint4*)(attst + (size_t)mb * 98304 + sst * 16384 + row7 * 128 + sl * 16) = ov;
    }
}

// ================= kernel B: out projection =================
// grid: 1024 m-blocks x 3 n-blocks = 3072. BM=128, BN=128, BK=64.
__global__ __launch_bounds__(256, 2)
void out_proj(const char* __restrict__ attst, const char* __restrict__ wos,
              const float* __restrict__ b_out, float* __restrict__ out)
{
    __shared__ __align__(16) char smem[65536];  // A 2x16K @0 ; B 2x16K @32768

    const int tid  = threadIdx.x;
    const int lane = tid & 63, wid = tid >> 6;
    const int g = lane >> 4, r16 = lane & 15;
    const int wm = wid >> 1, wn = wid & 1;

    int b = blockIdx.x;
    int L = (b & 7) * 384 + (b >> 3);
    const int mblk = L / 3, nblk = L - mblk * 3;

    auto stage = [&](int s, int buf) {
        const char* asrc = attst + (size_t)mblk * 98304 + s * 16384 + wid * 4096 + lane * 16;
        const char* bsrc = wos   + (size_t)nblk * 98304 + s * 16384 + wid * 4096 + lane * 16;
        char* adst = smem + buf * 16384 + wid * 4096;
        char* bdst = smem + 32768 + buf * 16384 + wid * 4096;
        #pragma unroll
        for (int j = 0; j < 4; ++j) {
            gload16(asrc + j * 1024, adst + j * 1024);
            gload16(bsrc + j * 1024, bdst + j * 1024);
        }
    };

    f32x4 acc[4][4] = {};
    auto compute = [&](int buf) {
        const char* ab = smem + buf * 16384;
        const char* bbp = smem + 32768 + buf * 16384;
        #pragma unroll
        for (int c = 0; c < 2; ++c) {
            const int sw = ((c * 4 + g) ^ (r16 & 7)) << 4;
            short8 a[4], bf[4];
            #pragma unroll
            for (int mi = 0; mi < 4; ++mi)
                a[mi] = *(const short8*)(ab + (wm * 64 + mi * 16 + r16) * 128 + sw);
            #pragma unroll
            for (int ni = 0; ni < 4; ++ni)
                bf[ni] = *(const short8*)(bbp + (wn * 64 + ni * 16 + r16) * 128 + sw);
            #pragma unroll
            for (int mi = 0; mi < 4; ++mi)
                #pragma unroll
                for (int ni = 0; ni < 4; ++ni)
                    acc[mi][ni] = MFMA16(a[mi], bf[ni], acc[mi][ni]);
        }
    };

    stage(0, 0);
    for (int s = 0; s < 6; ++s) {
        __syncthreads();
        if (s < 5) stage(s + 1, (s + 1) & 1);
        compute(s & 1);
    }

    float bias[4];
    #pragma unroll
    for (int ni = 0; ni < 4; ++ni) bias[ni] = b_out[nblk * 128 + wn * 64 + ni * 16 + r16];

    #pragma unroll
    for (int mi = 0; mi < 4; ++mi) {
        #pragma unroll
        for (int r = 0; r < 4; ++r) {
            int T = mblk * 128 + wm * 64 + mi * 16 + g * 4 + r;
            int win = T >> 4, tt = T & 15;
            int bb = win >> 8, wh = (win >> 4) & 15, ww = win & 15;
            size_t o = ((size_t)bb * 4096 + (wh * 4 + (tt >> 2)) * 64 + ww * 4 + (tt & 3)) * 384
                     + nblk * 128 + wn * 64;
            #pragma unroll
            for (int ni = 0; ni < 4; ++ni)
                out[o + ni * 16 + r16] = acc[mi][ni][r] + bias[ni];
        }
    }
}

extern "C" void kernel_launch(void* const* d_in, const int* in_sizes, int n_in,
                              void* d_out, int out_size, void* d_ws, size_t ws_size,
                              hipStream_t stream) {
    const float* x     = (const float*)d_in[0];
    const float* w_in  = (const float*)d_in[1];
    const float* b_in  = (const float*)d_in[2];
    const float* w_out = (const float*)d_in[3];
    const float* b_out = (const float*)d_in[4];
    float* out = (float*)d_out;

    char* ws = (char*)d_ws;
    char*  wst = ws + kWstOff;
    char*  wos = ws + kWosOff;
    float* brr = (float*)(ws + kBrrOff);
    char*  att = ws + kAttOff;

    prep<<<dim3(288), dim3(256), 0, stream>>>(w_in, b_in, w_out, wst, wos, brr);
    qkv_attn<<<dim3(12288), dim3(512), 0, stream>>>(x, wst, brr, att);
    out_proj<<<dim3(3072), dim3(256), 0, stream>>>(att, wos, b_out, out);
}

// Round 12
// 309.910 us; speedup vs baseline: 2.0484x; 2.0484x over previous
//
#include <hip/hip_runtime.h>
#include <hip/hip_bf16.h>

typedef __attribute__((ext_vector_type(8))) short short8;
typedef __attribute__((ext_vector_type(4))) float f32x4;

static __device__ __forceinline__ f32x4 MFMA16(short8 a, short8 b, f32x4 c) {
    return __builtin_amdgcn_mfma_f32_16x16x32_bf16(a, b, c, 0, 0, 0);
}
static __device__ __forceinline__ unsigned short f2bf(float f) {
    union { __hip_bfloat16 h; unsigned short u; } c;
    c.h = __float2bfloat16(f);
    return c.u;
}
static __device__ __forceinline__ void gload16(const void* g, void* l) {
    __builtin_amdgcn_global_load_lds(
        (const __attribute__((address_space(1))) unsigned int*)g,
        (__attribute__((address_space(3))) unsigned int*)l, 16, 0, 0);
}

// ---------------- ws layout ----------------
// wst  : bf16, LDS-order pre-swizzled w_in  [6 hp][6 s][1536 granules x16B] @ 0        (884736)
// wos  : bf16, LDS-order pre-swizzled w_out [3 nb][6 s][1024 granules x16B] @ 884736   (294912)
// brr  : f32  [12][96] head-major bias                                      @ 1179648  (4608)
// attst: bf16, LDS-order pre-swizzled att   [1024 mb][6 s][16384 B]         @ 1184256  (100663296)
// xbf  : bf16 fragment-ordered x  [1024 mb][6 s][8 f][2 c][64 lanes x16B] -> lives in d_out
//        total granules = 1024*6144 = 6291456 (100663296 B)
constexpr size_t kWstOff = 0;
constexpr size_t kWosOff = 884736;
constexpr size_t kBrrOff = 1179648;
constexpr size_t kAttOff = 1184256;

// ================= kernel 0: prep (convert + reorder + pre-swizzle weights) =====
__global__ void prep(const float* __restrict__ w_in, const float* __restrict__ b_in,
                     const float* __restrict__ w_out,
                     char* __restrict__ wst, char* __restrict__ wos,
                     float* __restrict__ brr)
{
    const int i = blockIdx.x * 256 + threadIdx.x;   // grid covers 73728 exactly
    if (i < 55296) {
        int hp = i / 9216, rem = i % 9216;
        int s = rem / 1536, slot16 = rem % 1536;
        int row = slot16 >> 3, sl = slot16 & 7;
        int c8 = sl ^ (row & 7);
        int hh = row / 96, rr = row % 96;
        int sec = rr >> 5, d = rr & 31;
        int srow = sec * 384 + (hp * 2 + hh) * 32 + d;
        int k0 = s * 64 + c8 * 8;
        const float4* src = (const float4*)(w_in + (size_t)srow * 384 + k0);
        float4 a = src[0], b = src[1];
        uint4 w;
        w.x = f2bf(a.x) | ((unsigned)f2bf(a.y) << 16);
        w.y = f2bf(a.z) | ((unsigned)f2bf(a.w) << 16);
        w.z = f2bf(b.x) | ((unsigned)f2bf(b.y) << 16);
        w.w = f2bf(b.z) | ((unsigned)f2bf(b.w) << 16);
        *(uint4*)(wst + (size_t)i * 16) = w;
    } else {
        int j = i - 55296;                           // [0, 18432)
        int nb = j / 6144, rem = j % 6144;
        int s = rem / 1024, slot16 = rem % 1024;
        int row = slot16 >> 3, sl = slot16 & 7;
        int c8 = sl ^ (row & 7);
        int srow = nb * 128 + row;
        int k0 = s * 64 + c8 * 8;
        const float4* src = (const float4*)(w_out + (size_t)srow * 384 + k0);
        float4 a = src[0], b = src[1];
        uint4 w;
        w.x = f2bf(a.x) | ((unsigned)f2bf(a.y) << 16);
        w.y = f2bf(a.z) | ((unsigned)f2bf(a.w) << 16);
        w.z = f2bf(b.x) | ((unsigned)f2bf(b.y) << 16);
        w.w = f2bf(b.z) | ((unsigned)f2bf(b.w) << 16);
        *(uint4*)(wos + (size_t)j * 16) = w;
    }
    if (i < 1152) {
        int h = i / 96, jj = i % 96;
        int sec = jj >> 5, d = jj & 31;
        brr[i] = b_in[sec * 384 + h * 32 + d];
    }
}

// ================= kernel 0b: prep_x — x (f32) -> MFMA-fragment-ordered bf16 ====
// granule i -> byte i*16 of xbf: i = mb*6144 + s*1024 + f*128 + c*64 + lane
// lane holds row (f*16 + (lane&15)) of mb's 128-token window-permuted slice,
// k = s*64 + c*32 + (lane>>4)*8 .. +8.  One wave's fragment = 1KB contiguous.
__global__ void prep_x(const float* __restrict__ x, char* __restrict__ xbf)
{
    const int i = blockIdx.x * 256 + threadIdx.x;    // grid covers 6291456 exactly
    const int lane = i & 63;
    const int cc = (i >> 6) & 1;
    const int f = (i >> 7) & 7;
    const int rem = i >> 10;                          // mb*6 + s
    const int s = rem % 6, mb = rem / 6;

    int T = mb * 128 + f * 16 + (lane & 15);
    int win = T >> 4, t4 = T & 15;
    int bb = win >> 8, wh = (win >> 4) & 15, ww = win & 15;
    int n = (wh * 4 + (t4 >> 2)) * 64 + ww * 4 + (t4 & 3);
    int k0 = s * 64 + cc * 32 + (lane >> 4) * 8;

    const float4* src = (const float4*)(x + ((size_t)bb * 4096 + n) * 384 + k0);
    float4 a = src[0], b = src[1];
    uint4 w;
    w.x = f2bf(a.x) | ((unsigned)f2bf(a.y) << 16);
    w.y = f2bf(a.z) | ((unsigned)f2bf(a.w) << 16);
    w.z = f2bf(b.x) | ((unsigned)f2bf(b.y) << 16);
    w.w = f2bf(b.z) | ((unsigned)f2bf(b.w) << 16);
    *(uint4*)(xbf + (size_t)i * 16) = w;
}

// ================= kernel A: QKV projection + window attention =================
// grid: 1024 m-blocks x 6 head-pairs = 6144. block = 512 thr (8 waves).
// BM=128 (8 windows), BN=192 (2 heads x q32|k32|v32), BK=64. wave tile 64x48.
// A: coalesced fragment loads from xbf (global, L1/L2-hot), NO LDS, NO cvt VALU.
// B: gload16 double-buffered, LDS 48KB, ONE barrier per K-step.
// attn alias: QKV^T tiles [8 win][2 head][3 sec][32 d][16 t] @0 (48KB exactly)
__global__ __launch_bounds__(512, 2)
void qkv_attn(const char* __restrict__ xbf, const char* __restrict__ wst,
              const float* __restrict__ brr, char* __restrict__ attst)
{
    __shared__ __align__(16) char smem[49152];

    const int tid  = threadIdx.x;
    const int lane = tid & 63, wid = tid >> 6;         // 8 waves
    const int g = lane >> 4, r16 = lane & 15;
    const int wm = wid >> 2, wn = wid & 3;             // wm 0..1 (M64), wn 0..3 (N48)

    int b = blockIdx.x;
    int L = (b & 7) * 768 + (b >> 3);          // XCD-chunked swizzle (6144 % 8 == 0)
    const int mblk = L / 6, hp = L - mblk * 6;

    const char* xb = xbf + (size_t)mblk * 98304;       // this block's A slice
    const char* wst_blk = wst + (size_t)hp * 147456;
    auto stage_B = [&](int s, int buf) {
        char* dst = smem + buf * 24576 + tid * 16;
        const char* src = wst_blk + s * 24576 + tid * 16;
        #pragma unroll
        for (int j = 0; j < 3; ++j) gload16(src + j * 8192, dst + j * 8192);
    };

    f32x4 acc[4][3] = {};
    auto compute = [&](int s, int buf) {
        const char* bbp = smem + buf * 24576;
        const char* xs = xb + (size_t)s * 16384 + (size_t)(wm * 8) * 1024 + lane * 16;
        short8 a[4][2];
        #pragma unroll
        for (int mi = 0; mi < 4; ++mi)
            #pragma unroll
            for (int c = 0; c < 2; ++c)
                a[mi][c] = *(const short8*)(xs + (mi * 2 + c) * 1024);
        #pragma unroll
        for (int c = 0; c < 2; ++c) {
            const int sw = ((c * 4 + g) ^ (r16 & 7)) << 4;
            short8 bf[3];
            #pragma unroll
            for (int ni = 0; ni < 3; ++ni)
                bf[ni] = *(const short8*)(bbp + (wn * 48 + ni * 16 + r16) * 128 + sw);
            #pragma unroll
            for (int mi = 0; mi < 4; ++mi)
                #pragma unroll
                for (int ni = 0; ni < 3; ++ni)
                    acc[mi][ni] = MFMA16(a[mi][c], bf[ni], acc[mi][ni]);
        }
    };

    // main loop: B double-buffered, ONE barrier per step; A streams from xbf
    stage_B(0, 0);
    for (int s = 0; s < 6; ++s) {
        __syncthreads();                       // B(s) DMA drained
        if (s < 5) stage_B(s + 1, (s + 1) & 1);
        compute(s, s & 1);
    }
    __syncthreads();  // attn tiles alias BOTH B buffers: wait all compute reads done

    // ---- epilogue: acc (+bias) -> Q^T/K^T/V^T tiles [win][head][sec][d][t] ----
    #pragma unroll
    for (int mi = 0; mi < 4; ++mi) {
        const int win = wm * 4 + mi;
        #pragma unroll
        for (int ni = 0; ni < 3; ++ni) {
            const int cb = wn * 48 + ni * 16;   // col base in [0,192), 16-aligned
            const int hl = cb / 96;             // head-local 0/1
            const int w96 = cb - hl * 96;
            const int sec = w96 >> 5;           // 0=Q 1=K 2=V
            const int d = (w96 & 31) + r16;
            const float bias = brr[(hp * 2 + hl) * 96 + w96 + r16];
            float v0 = acc[mi][ni][0] + bias;
            float v1 = acc[mi][ni][1] + bias;
            float v2 = acc[mi][ni][2] + bias;
            float v3 = acc[mi][ni][3] + bias;
            uint2 w;
            w.x = f2bf(v0) | ((unsigned)f2bf(v1) << 16);
            w.y = f2bf(v2) | ((unsigned)f2bf(v3) << 16);
            *(uint2*)(smem + win * 6144 + hl * 3072 + sec * 1024 + d * 32 + g * 8) = w;
        }
    }
    __syncthreads();  // tiles written cross-wave: rendezvous before attn

    // ---- attention: wave wid owns window wid, loops over its 2 heads ----
    const float kC = 0.17677669529663687f * 1.4426950408889634f;  // (1/sqrt32)*log2e
    const f32x4 zero = {0.f, 0.f, 0.f, 0.f};
    const int win = wid;
    #pragma unroll
    for (int hl = 0; hl < 2; ++hl) {
        char* base = smem + win * 6144 + hl * 3072;

        union U8 { unsigned short e[8]; short8 v; };
        U8 ku, qu;
        #pragma unroll
        for (int j = 0; j < 8; ++j) {
            const int off = (g * 8 + j) * 32 + r16 * 2;   // elem (d, t=r16)
            qu.e[j] = *(const unsigned short*)(base + off);
            ku.e[j] = *(const unsigned short*)(base + 1024 + off);
        }
        f32x4 s = MFMA16(ku.v, qu.v, zero);     // D[key=4g+r][q=r16]

        float m = fmaxf(fmaxf(s[0], s[1]), fmaxf(s[2], s[3]));
        m = fmaxf(m, __shfl_xor(m, 16, 64));
        m = fmaxf(m, __shfl_xor(m, 32, 64));
        float p[4], sum = 0.f;
        #pragma unroll
        for (int r = 0; r < 4; ++r) { p[r] = exp2f((s[r] - m) * kC); sum += p[r]; }
        sum += __shfl_xor(sum, 16, 64);
        sum += __shfl_xor(sum, 32, 64);
        const float inv = 1.f / sum;

        // P as in-register A-fragment under k-perm k=4g+j (upper 4 elems zero);
        // V's B-fragment uses the SAME key permutation.
        U8 pu;
        pu.e[0] = f2bf(p[0] * inv); pu.e[1] = f2bf(p[1] * inv);
        pu.e[2] = f2bf(p[2] * inv); pu.e[3] = f2bf(p[3] * inv);
        pu.e[4] = 0; pu.e[5] = 0; pu.e[6] = 0; pu.e[7] = 0;

        f32x4 o[2];
        #pragma unroll
        for (int ti = 0; ti < 2; ++ti) {
            U8 vu;                               // V[key=4g+j][d=ti*16+r16]
            *(uint2*)&vu.e[0] = *(const uint2*)(base + 2048 + (ti * 16 + r16) * 32 + g * 8);
            vu.e[4] = 0; vu.e[5] = 0; vu.e[6] = 0; vu.e[7] = 0;
            o[ti] = MFMA16(pu.v, vu.v, zero);    // D[q=4g+r][d-col=r16]
        }

        // transpose o via own tile's (dead) Q area -> [t][64B] rows,
        // then ONE uint4 global store per lane into attst's granule layout.
        #pragma unroll
        for (int ti = 0; ti < 2; ++ti)
            #pragma unroll
            for (int r = 0; r < 4; ++r)
                *(unsigned short*)(base + (g * 4 + r) * 64 + (ti * 16 + r16) * 2)
                    = f2bf(o[ti][r]);
        uint4 ov = *(const uint4*)(base + r16 * 64 + g * 16);  // same-wave RAW

        const int ghead = hp * 2 + hl;
        int row7 = win * 16 + r16;               // row within this mblk (BM=128)
        int col8 = ghead * 4 + g;                // 16B-granule column index
        int sst = col8 >> 3;
        int sl = (col8 & 7) ^ (row7 & 7);
        *(uint4*)(attst + (size_t)mblk * 98304 + sst * 16384 + row7 * 128 + sl * 16) = ov;
    }
}

// ================= kernel B: out projection =================
// grid: 1024 m-blocks x 3 n-blocks = 3072. BM=128, BN=128, BK=64.
__global__ __launch_bounds__(256, 2)
void out_proj(const char* __restrict__ attst, const char* __restrict__ wos,
              const float* __restrict__ b_out, float* __restrict__ out)
{
    __shared__ __align__(16) char smem[65536];  // A 2x16K @0 ; B 2x16K @32768

    const int tid  = threadIdx.x;
    const int lane = tid & 63, wid = tid >> 6;
    const int g = lane >> 4, r16 = lane & 15;
    const int wm = wid >> 1, wn = wid & 1;

    int b = blockIdx.x;
    int L = (b & 7) * 384 + (b >> 3);
    const int mblk = L / 3, nblk = L - mblk * 3;

    auto stage = [&](int s, int buf) {
        const char* asrc = attst + (size_t)mblk * 98304 + s * 16384 + wid * 4096 + lane * 16;
        const char* bsrc = wos   + (size_t)nblk * 98304 + s * 16384 + wid * 4096 + lane * 16;
        char* adst = smem + buf * 16384 + wid * 4096;
        char* bdst = smem + 32768 + buf * 16384 + wid * 4096;
        #pragma unroll
        for (int j = 0; j < 4; ++j) {
            gload16(asrc + j * 1024, adst + j * 1024);
            gload16(bsrc + j * 1024, bdst + j * 1024);
        }
    };

    f32x4 acc[4][4] = {};
    auto compute = [&](int buf) {
        const char* ab = smem + buf * 16384;
        const char* bbp = smem + 32768 + buf * 16384;
        #pragma unroll
        for (int c = 0; c < 2; ++c) {
            const int sw = ((c * 4 + g) ^ (r16 & 7)) << 4;
            short8 a[4], bf[4];
            #pragma unroll
            for (int mi = 0; mi < 4; ++mi)
                a[mi] = *(const short8*)(ab + (wm * 64 + mi * 16 + r16) * 128 + sw);
            #pragma unroll
            for (int ni = 0; ni < 4; ++ni)
                bf[ni] = *(const short8*)(bbp + (wn * 64 + ni * 16 + r16) * 128 + sw);
            #pragma unroll
            for (int mi = 0; mi < 4; ++mi)
                #pragma unroll
                for (int ni = 0; ni < 4; ++ni)
                    acc[mi][ni] = MFMA16(a[mi], bf[ni], acc[mi][ni]);
        }
    };

    stage(0, 0);
    for (int s = 0; s < 6; ++s) {
        __syncthreads();
        if (s < 5) stage(s + 1, (s + 1) & 1);
        compute(s & 1);
    }

    float bias[4];
    #pragma unroll
    for (int ni = 0; ni < 4; ++ni) bias[ni] = b_out[nblk * 128 + wn * 64 + ni * 16 + r16];

    #pragma unroll
    for (int mi = 0; mi < 4; ++mi) {
        #pragma unroll
        for (int r = 0; r < 4; ++r) {
            int T = mblk * 128 + wm * 64 + mi * 16 + g * 4 + r;
            int win = T >> 4, tt = T & 15;
            int bb = win >> 8, wh = (win >> 4) & 15, ww = win & 15;
            size_t o = ((size_t)bb * 4096 + (wh * 4 + (tt >> 2)) * 64 + ww * 4 + (tt & 3)) * 384
                     + nblk * 128 + wn * 64;
            #pragma unroll
            for (int ni = 0; ni < 4; ++ni)
                out[o + ni * 16 + r16] = acc[mi][ni][r] + bias[ni];
        }
    }
}

extern "C" void kernel_launch(void* const* d_in, const int* in_sizes, int n_in,
                              void* d_out, int out_size, void* d_ws, size_t ws_size,
                              hipStream_t stream) {
    const float* x     = (const float*)d_in[0];
    const float* w_in  = (const float*)d_in[1];
    const float* b_in  = (const float*)d_in[2];
    const float* w_out = (const float*)d_in[3];
    const float* b_out = (const float*)d_in[4];
    float* out = (float*)d_out;

    char* ws = (char*)d_ws;
    char*  wst = ws + kWstOff;
    char*  wos = ws + kWosOff;
    float* brr = (float*)(ws + kBrrOff);
    char*  att = ws + kAttOff;
    // xbf scratch lives in d_out: written by prep_x, consumed by qkv_attn,
    // then fully overwritten by out_proj (stream-ordered, deterministic).
    char*  xbf = (char*)d_out;

    prep<<<dim3(288), dim3(256), 0, stream>>>(w_in, b_in, w_out, wst, wos, brr);
    prep_x<<<dim3(24576), dim3(256), 0, stream>>>(x, xbf);
    qkv_attn<<<dim3(6144), dim3(512), 0, stream>>>(xbf, wst, brr, att);
    out_proj<<<dim3(3072), dim3(256), 0, stream>>>(att, wos, b_out, out);
}

// Round 13
// 273.952 us; speedup vs baseline: 2.3173x; 1.1313x over previous
//
#include <hip/hip_runtime.h>
#include <hip/hip_bf16.h>

typedef __attribute__((ext_vector_type(8))) short short8;
typedef __attribute__((ext_vector_type(4))) float f32x4;

static __device__ __forceinline__ f32x4 MFMA16(short8 a, short8 b, f32x4 c) {
    return __builtin_amdgcn_mfma_f32_16x16x32_bf16(a, b, c, 0, 0, 0);
}
static __device__ __forceinline__ unsigned short f2bf(float f) {
    union { __hip_bfloat16 h; unsigned short u; } c;
    c.h = __float2bfloat16(f);
    return c.u;
}
static __device__ __forceinline__ void gload16(const void* g, void* l) {
    __builtin_amdgcn_global_load_lds(
        (const __attribute__((address_space(1))) unsigned int*)g,
        (__attribute__((address_space(3))) unsigned int*)l, 16, 0, 0);
}

// ---------------- ws layout ----------------
// wst  : bf16, LDS-order pre-swizzled w_in  [6 hp][6 s][1536 granules x16B] @ 0        (884736)
// wos  : bf16, LDS-order pre-swizzled w_out [3 nb][6 s][1024 granules x16B] @ 884736   (294912)
// brr  : f32  [12][96] head-major bias                                      @ 1179648  (4608)
// attst: bf16, LDS-order pre-swizzled att   [1024 mb][6 s][16384 B]         @ 1184256  (100663296)
// xbf  : bf16 fragment-ordered x  [1024 mb][6 s][8 f][2 c][64 lanes x16B] -> lives in d_out
constexpr size_t kWstOff = 0;
constexpr size_t kWosOff = 884736;
constexpr size_t kBrrOff = 1179648;
constexpr size_t kAttOff = 1184256;

// ================= kernel 0: prep (convert + reorder + pre-swizzle weights) =====
__global__ void prep(const float* __restrict__ w_in, const float* __restrict__ b_in,
                     const float* __restrict__ w_out,
                     char* __restrict__ wst, char* __restrict__ wos,
                     float* __restrict__ brr)
{
    const int i = blockIdx.x * 256 + threadIdx.x;   // grid covers 73728 exactly
    if (i < 55296) {
        int hp = i / 9216, rem = i % 9216;
        int s = rem / 1536, slot16 = rem % 1536;
        int row = slot16 >> 3, sl = slot16 & 7;
        int c8 = sl ^ (row & 7);
        int hh = row / 96, rr = row % 96;
        int sec = rr >> 5, d = rr & 31;
        int srow = sec * 384 + (hp * 2 + hh) * 32 + d;
        int k0 = s * 64 + c8 * 8;
        const float4* src = (const float4*)(w_in + (size_t)srow * 384 + k0);
        float4 a = src[0], b = src[1];
        uint4 w;
        w.x = f2bf(a.x) | ((unsigned)f2bf(a.y) << 16);
        w.y = f2bf(a.z) | ((unsigned)f2bf(a.w) << 16);
        w.z = f2bf(b.x) | ((unsigned)f2bf(b.y) << 16);
        w.w = f2bf(b.z) | ((unsigned)f2bf(b.w) << 16);
        *(uint4*)(wst + (size_t)i * 16) = w;
    } else {
        int j = i - 55296;                           // [0, 18432)
        int nb = j / 6144, rem = j % 6144;
        int s = rem / 1024, slot16 = rem % 1024;
        int row = slot16 >> 3, sl = slot16 & 7;
        int c8 = sl ^ (row & 7);
        int srow = nb * 128 + row;
        int k0 = s * 64 + c8 * 8;
        const float4* src = (const float4*)(w_out + (size_t)srow * 384 + k0);
        float4 a = src[0], b = src[1];
        uint4 w;
        w.x = f2bf(a.x) | ((unsigned)f2bf(a.y) << 16);
        w.y = f2bf(a.z) | ((unsigned)f2bf(a.w) << 16);
        w.z = f2bf(b.x) | ((unsigned)f2bf(b.y) << 16);
        w.w = f2bf(b.z) | ((unsigned)f2bf(b.w) << 16);
        *(uint4*)(wos + (size_t)j * 16) = w;
    }
    if (i < 1152) {
        int h = i / 96, jj = i % 96;
        int sec = jj >> 5, d = jj & 31;
        brr[i] = b_in[sec * 384 + h * 32 + d];
    }
}

// ================= kernel 0b: prep_x — x (f32) -> MFMA-fragment-ordered bf16 ====
__global__ void prep_x(const float* __restrict__ x, char* __restrict__ xbf)
{
    const int i = blockIdx.x * 256 + threadIdx.x;    // grid covers 6291456 exactly
    const int lane = i & 63;
    const int cc = (i >> 6) & 1;
    const int f = (i >> 7) & 7;
    const int rem = i >> 10;                          // mb*6 + s
    const int s = rem % 6, mb = rem / 6;

    int T = mb * 128 + f * 16 + (lane & 15);
    int win = T >> 4, t4 = T & 15;
    int bb = win >> 8, wh = (win >> 4) & 15, ww = win & 15;
    int n = (wh * 4 + (t4 >> 2)) * 64 + ww * 4 + (t4 & 3);
    int k0 = s * 64 + cc * 32 + (lane >> 4) * 8;

    const float4* src = (const float4*)(x + ((size_t)bb * 4096 + n) * 384 + k0);
    float4 a = src[0], b = src[1];
    uint4 w;
    w.x = f2bf(a.x) | ((unsigned)f2bf(a.y) << 16);
    w.y = f2bf(a.z) | ((unsigned)f2bf(a.w) << 16);
    w.z = f2bf(b.x) | ((unsigned)f2bf(b.y) << 16);
    w.w = f2bf(b.z) | ((unsigned)f2bf(b.w) << 16);
    *(uint4*)(xbf + (size_t)i * 16) = w;
}

// ================= kernel A: QKV projection + window attention =================
// grid: 1024 m-blocks x 6 head-pairs = 6144. block = 512 thr (8 waves).
// BM=128, BN=192, BK=64. wave split 4x2: wm 0..3 (M32), wn 0..1 (N96) -> acc[2][6].
// A: coalesced fragment loads from xbf; issued BEFORE the B DMA so MFMA's vmcnt
//    waits do NOT drain the next-step DMA (issue-order counting).
// B: gload16 double-buffered, LDS 48KB, ONE barrier per K-step.
// attn alias: QKV^T tiles [8 win][2 head][3 sec][32 d][16 t] @0 (48KB exactly)
__global__ __launch_bounds__(512, 2)
void qkv_attn(const char* __restrict__ xbf, const char* __restrict__ wst,
              const float* __restrict__ brr, char* __restrict__ attst)
{
    __shared__ __align__(16) char smem[49152];

    const int tid  = threadIdx.x;
    const int lane = tid & 63, wid = tid >> 6;         // 8 waves
    const int g = lane >> 4, r16 = lane & 15;
    const int wm = wid >> 1, wn = wid & 1;             // wm 0..3 (M32), wn 0..1 (N96)

    int b = blockIdx.x;
    int L = (b & 7) * 768 + (b >> 3);          // XCD-chunked swizzle (6144 % 8 == 0)
    const int mblk = L / 6, hp = L - mblk * 6;
    const int head = hp * 2 + wn;

    const char* xb = xbf + (size_t)mblk * 98304;       // this block's A slice
    const char* wst_blk = wst + (size_t)hp * 147456;
    auto stage_B = [&](int s, int buf) {
        char* dst = smem + buf * 24576 + tid * 16;
        const char* src = wst_blk + s * 24576 + tid * 16;
        #pragma unroll
        for (int j = 0; j < 3; ++j) gload16(src + j * 8192, dst + j * 8192);
    };

    f32x4 acc[2][6] = {};

    // main loop: ONE barrier/step. Order inside step: A-loads (oldest) ->
    // sched_barrier -> next-step DMA (newest) -> ds_reads+MFMA (vmcnt waits
    // cover only the A-loads; DMAs stay in flight across the MFMA phase).
    stage_B(0, 0);
    for (int s = 0; s < 6; ++s) {
        __syncthreads();                       // B(s) + A(s)-irrelevant drain
        short8 a[2][2];
        {
            const char* xs = xb + (size_t)s * 16384 + lane * 16;
            #pragma unroll
            for (int mi = 0; mi < 2; ++mi)
                #pragma unroll
                for (int c = 0; c < 2; ++c)
                    a[mi][c] = *(const short8*)(xs + ((wm * 2 + mi) * 2048 + c * 1024));
        }
        __builtin_amdgcn_sched_barrier(0);     // pin: DMA issues AFTER A-loads
        if (s < 5) stage_B(s + 1, (s + 1) & 1);

        const char* bbp = smem + (s & 1) * 24576;
        #pragma unroll
        for (int c = 0; c < 2; ++c) {
            const int sw = ((c * 4 + g) ^ (r16 & 7)) << 4;
            short8 bf[6];
            #pragma unroll
            for (int ni = 0; ni < 6; ++ni)
                bf[ni] = *(const short8*)(bbp + (wn * 96 + ni * 16 + r16) * 128 + sw);
            #pragma unroll
            for (int mi = 0; mi < 2; ++mi)
                #pragma unroll
                for (int ni = 0; ni < 6; ++ni)
                    acc[mi][ni] = MFMA16(a[mi][c], bf[ni], acc[mi][ni]);
        }
    }
    __syncthreads();  // attn tiles alias BOTH B buffers: wait all compute reads done

    // ---- epilogue: acc (+bias) -> Q^T/K^T/V^T tiles [win][head][sec][d][t] ----
    float bias[6];
    #pragma unroll
    for (int ni = 0; ni < 6; ++ni) bias[ni] = brr[head * 96 + ni * 16 + r16];

    #pragma unroll
    for (int mi = 0; mi < 2; ++mi) {
        const int win = wm * 2 + mi;
        #pragma unroll
        for (int ni = 0; ni < 6; ++ni) {
            const int sec = ni >> 1;            // 0=Q 1=K 2=V
            const int d = (ni & 1) * 16 + r16;
            float v0 = acc[mi][ni][0] + bias[ni];
            float v1 = acc[mi][ni][1] + bias[ni];
            float v2 = acc[mi][ni][2] + bias[ni];
            float v3 = acc[mi][ni][3] + bias[ni];
            uint2 w;
            w.x = f2bf(v0) | ((unsigned)f2bf(v1) << 16);
            w.y = f2bf(v2) | ((unsigned)f2bf(v3) << 16);
            *(uint2*)(smem + win * 6144 + wn * 3072 + sec * 1024 + d * 32 + g * 8) = w;
        }
    }
    // tiles are wave-local (wave (wm,wn) wrote windows wm*2..+1, head wn): no barrier

    // ---- attention: 2 windows per wave, zero barriers, P stays in registers ----
    const float kC = 0.17677669529663687f * 1.4426950408889634f;  // (1/sqrt32)*log2e
    const f32x4 zero = {0.f, 0.f, 0.f, 0.f};

    #pragma unroll
    for (int i = 0; i < 2; ++i) {
        const int win = wm * 2 + i;
        char* base = smem + win * 6144 + wn * 3072;

        union U8 { unsigned short e[8]; short8 v; };
        U8 ku, qu;
        #pragma unroll
        for (int j = 0; j < 8; ++j) {
            const int off = (g * 8 + j) * 32 + r16 * 2;   // elem (d, t=r16)
            qu.e[j] = *(const unsigned short*)(base + off);
            ku.e[j] = *(const unsigned short*)(base + 1024 + off);
        }
        f32x4 s = MFMA16(ku.v, qu.v, zero);     // D[key=4g+r][q=r16]

        float m = fmaxf(fmaxf(s[0], s[1]), fmaxf(s[2], s[3]));
        m = fmaxf(m, __shfl_xor(m, 16, 64));
        m = fmaxf(m, __shfl_xor(m, 32, 64));
        float p[4], sum = 0.f;
        #pragma unroll
        for (int r = 0; r < 4; ++r) { p[r] = exp2f((s[r] - m) * kC); sum += p[r]; }
        sum += __shfl_xor(sum, 16, 64);
        sum += __shfl_xor(sum, 32, 64);
        const float inv = 1.f / sum;

        // P as in-register A-fragment under k-perm k=4g+j (upper 4 elems zero);
        // V's B-fragment uses the SAME key permutation.
        U8 pu;
        pu.e[0] = f2bf(p[0] * inv); pu.e[1] = f2bf(p[1] * inv);
        pu.e[2] = f2bf(p[2] * inv); pu.e[3] = f2bf(p[3] * inv);
        pu.e[4] = 0; pu.e[5] = 0; pu.e[6] = 0; pu.e[7] = 0;

        f32x4 o[2];
        #pragma unroll
        for (int ti = 0; ti < 2; ++ti) {
            U8 vu;                               // V[key=4g+j][d=ti*16+r16]
            *(uint2*)&vu.e[0] = *(const uint2*)(base + 2048 + (ti * 16 + r16) * 32 + g * 8);
            vu.e[4] = 0; vu.e[5] = 0; vu.e[6] = 0; vu.e[7] = 0;
            o[ti] = MFMA16(pu.v, vu.v, zero);    // D[q=4g+r][d-col=r16]
        }

        // transpose o via own tile's (dead) Q area -> [t][64B] rows,
        // then ONE uint4 global store per lane into attst's granule layout.
        #pragma unroll
        for (int ti = 0; ti < 2; ++ti)
            #pragma unroll
            for (int r = 0; r < 4; ++r)
                *(unsigned short*)(base + (g * 4 + r) * 64 + (ti * 16 + r16) * 2)
                    = f2bf(o[ti][r]);
        uint4 ov = *(const uint4*)(base + r16 * 64 + g * 16);  // same-wave RAW

        const int ghead = hp * 2 + wn;
        int row7 = win * 16 + r16;               // row within this mblk (BM=128)
        int col8 = ghead * 4 + g;                // 16B-granule column index
        int sst = col8 >> 3;
        int sl = (col8 & 7) ^ (row7 & 7);
        *(uint4*)(attst + (size_t)mblk * 98304 + sst * 16384 + row7 * 128 + sl * 16) = ov;
    }
}

// ================= kernel B: out projection =================
// grid: 1024 m-blocks x 3 n-blocks = 3072. BM=128, BN=128, BK=64.
__global__ __launch_bounds__(256, 2)
void out_proj(const char* __restrict__ attst, const char* __restrict__ wos,
              const float* __restrict__ b_out, float* __restrict__ out)
{
    __shared__ __align__(16) char smem[65536];  // A 2x16K @0 ; B 2x16K @32768

    const int tid  = threadIdx.x;
    const int lane = tid & 63, wid = tid >> 6;
    const int g = lane >> 4, r16 = lane & 15;
    const int wm = wid >> 1, wn = wid & 1;

    int b = blockIdx.x;
    int L = (b & 7) * 384 + (b >> 3);
    const int mblk = L / 3, nblk = L - mblk * 3;

    auto stage = [&](int s, int buf) {
        const char* asrc = attst + (size_t)mblk * 98304 + s * 16384 + wid * 4096 + lane * 16;
        const char* bsrc = wos   + (size_t)nblk * 98304 + s * 16384 + wid * 4096 + lane * 16;
        char* adst = smem + buf * 16384 + wid * 4096;
        char* bdst = smem + 32768 + buf * 16384 + wid * 4096;
        #pragma unroll
        for (int j = 0; j < 4; ++j) {
            gload16(asrc + j * 1024, adst + j * 1024);
            gload16(bsrc + j * 1024, bdst + j * 1024);
        }
    };

    f32x4 acc[4][4] = {};
    auto compute = [&](int buf) {
        const char* ab = smem + buf * 16384;
        const char* bbp = smem + 32768 + buf * 16384;
        #pragma unroll
        for (int c = 0; c < 2; ++c) {
            const int sw = ((c * 4 + g) ^ (r16 & 7)) << 4;
            short8 a[4], bf[4];
            #pragma unroll
            for (int mi = 0; mi < 4; ++mi)
                a[mi] = *(const short8*)(ab + (wm * 64 + mi * 16 + r16) * 128 + sw);
            #pragma unroll
            for (int ni = 0; ni < 4; ++ni)
                bf[ni] = *(const short8*)(bbp + (wn * 64 + ni * 16 + r16) * 128 + sw);
            #pragma unroll
            for (int mi = 0; mi < 4; ++mi)
                #pragma unroll
                for (int ni = 0; ni < 4; ++ni)
                    acc[mi][ni] = MFMA16(a[mi], bf[ni], acc[mi][ni]);
        }
    };

    stage(0, 0);
    for (int s = 0; s < 6; ++s) {
        __syncthreads();
        if (s < 5) stage(s + 1, (s + 1) & 1);
        compute(s & 1);
    }

    float bias[4];
    #pragma unroll
    for (int ni = 0; ni < 4; ++ni) bias[ni] = b_out[nblk * 128 + wn * 64 + ni * 16 + r16];

    #pragma unroll
    for (int mi = 0; mi < 4; ++mi) {
        #pragma unroll
        for (int r = 0; r < 4; ++r) {
            int T = mblk * 128 + wm * 64 + mi * 16 + g * 4 + r;
            int win = T >> 4, tt = T & 15;
            int bb = win >> 8, wh = (win >> 4) & 15, ww = win & 15;
            size_t o = ((size_t)bb * 4096 + (wh * 4 + (tt >> 2)) * 64 + ww * 4 + (tt & 3)) * 384
                     + nblk * 128 + wn * 64;
            #pragma unroll
            for (int ni = 0; ni < 4; ++ni)
                out[o + ni * 16 + r16] = acc[mi][ni][r] + bias[ni];
        }
    }
}

extern "C" void kernel_launch(void* const* d_in, const int* in_sizes, int n_in,
                              void* d_out, int out_size, void* d_ws, size_t ws_size,
                              hipStream_t stream) {
    const float* x     = (const float*)d_in[0];
    const float* w_in  = (const float*)d_in[1];
    const float* b_in  = (const float*)d_in[2];
    const float* w_out = (const float*)d_in[3];
    const float* b_out = (const float*)d_in[4];
    float* out = (float*)d_out;

    char* ws = (char*)d_ws;
    char*  wst = ws + kWstOff;
    char*  wos = ws + kWosOff;
    float* brr = (float*)(ws + kBrrOff);
    char*  att = ws + kAttOff;
    // xbf scratch lives in d_out: written by prep_x, consumed by qkv_attn,
    // then fully overwritten by out_proj (stream-ordered, deterministic).
    char*  xbf = (char*)d_out;

    prep<<<dim3(288), dim3(256), 0, stream>>>(w_in, b_in, w_out, wst, wos, brr);
    prep_x<<<dim3(24576), dim3(256), 0, stream>>>(x, xbf);
    qkv_attn<<<dim3(6144), dim3(512), 0, stream>>>(xbf, wst, brr, att);
    out_proj<<<dim3(3072), dim3(256), 0, stream>>>(att, wos, b_out, out);
}